// Round 1
// baseline (945.105 us; speedup 1.0000x reference)
//
#include <hip/hip_runtime.h>
#include <hip/hip_bf16.h>

#define Nn 3072
#define E_IN 98304
#define EP (E_IN + Nn)      // 101376 edges incl self loops
#define CAP 128             // per-node bucket capacity (Poisson(32) -> never exceeded)
#define NNsq ((size_t)Nn * (size_t)Nn)

__device__ __forceinline__ float eluf(float a) { return a > 0.f ? a : (expf(a) - 1.f); }

// ---------- softmax of s1 rows + entropy partial ----------
__global__ __launch_bounds__(256) void k_softmax(const float* __restrict__ s1,
                                                 float* __restrict__ s_soft,
                                                 float* __restrict__ scal) {
    int n = blockIdx.x * 256 + threadIdx.x;   // 12*256 = 3072
    float v[16], mx = -1e30f;
#pragma unroll
    for (int i = 0; i < 16; i++) { v[i] = s1[n * 16 + i]; mx = fmaxf(mx, v[i]); }
    float s = 0.f;
#pragma unroll
    for (int i = 0; i < 16; i++) { v[i] = expf(v[i] - mx); s += v[i]; }
    float inv = 1.f / s, ent = 0.f;
#pragma unroll
    for (int i = 0; i < 16; i++) {
        float p = v[i] * inv;
        s_soft[n * 16 + i] = p;
        ent += p * logf(p + 1e-15f);
    }
    __shared__ float wsum[4];
    for (int off = 32; off; off >>= 1) ent += __shfl_xor(ent, off);
    if ((threadIdx.x & 63) == 0) wsum[threadIdx.x >> 6] = ent;
    __syncthreads();
    if (threadIdx.x == 0) atomicAdd(&scal[2], wsum[0] + wsum[1] + wsum[2] + wsum[3]);
}

// ---------- M = S^T S partials -> Mbuf[256]; sum(M^2) = sum_nm P^2 done in k_fc ----------
__global__ __launch_bounds__(256) void k_psq(const float* __restrict__ s_soft,
                                             float* __restrict__ Mbuf) {
    __shared__ float sL[256 * 16];            // 16 KB: 256 rows of s
    int tid = threadIdx.x;
    int n0 = blockIdx.x * 256;                // 12 blocks
    for (int l = tid; l < 4096; l += 256) sL[l] = s_soft[(size_t)n0 * 16 + l];
    __syncthreads();
    int i = tid >> 4, j = tid & 15;
    float acc = 0.f;
#pragma unroll 8
    for (int n = 0; n < 256; n++) acc += sL[n * 16 + i] * sL[n * 16 + j];
    atomicAdd(&Mbuf[tid], acc);
}

// ---------- bucket edges by destination (row) ----------
__global__ void k_bucket(const int* __restrict__ ei, int* __restrict__ counts,
                         int* __restrict__ bucket) {
    int e = blockIdx.x * 256 + threadIdx.x;   // 396*256 = 101376
    if (e >= EP) return;
    int r = (e < E_IN) ? ei[e] : (e - E_IN);
    int pos = atomicAdd(&counts[r], 1);
    if (pos < CAP) bucket[r * CAP + pos] = e;
}

// ---------- h1 = x @ w1  [3072,128]x[128,32] ----------
__global__ __launch_bounds__(256) void k_gemm1(const float* __restrict__ x,
                                               const float* __restrict__ w1,
                                               float* __restrict__ h1) {
    __shared__ float xs[8 * 128];
    int n0 = blockIdx.x * 8;
    for (int idx = threadIdx.x; idx < 1024; idx += 256) xs[idx] = x[(size_t)n0 * 128 + idx];
    __syncthreads();
    int r = threadIdx.x >> 5, j = threadIdx.x & 31;
    float acc = 0.f;
#pragma unroll 8
    for (int k = 0; k < 128; k++) acc += xs[r * 128 + k] * w1[k * 32 + j];
    h1[(n0 + r) * 32 + j] = acc;
}

// ---------- EGAT layer 1: one wave per node ----------
__global__ __launch_bounds__(256) void k_egat1(const int* __restrict__ ei,
                                               const float* __restrict__ ea,
                                               const float* __restrict__ a1,
                                               const float* __restrict__ h1,
                                               const int* __restrict__ counts,
                                               const int* __restrict__ bucket,
                                               float* __restrict__ e1,
                                               float* __restrict__ hL1) {
    __shared__ float a1s[64];
    __shared__ float alphaL[4][CAP][4];
    __shared__ float eaL[4][CAP][3];
    __shared__ int   colL[4][CAP];
    int tid = threadIdx.x, w = tid >> 6, lane = tid & 63;
    if (tid < 64) a1s[tid] = a1[tid];
    __syncthreads();
    int n = blockIdx.x * 4 + w;
    int deg = counts[n]; if (deg > CAP) deg = CAP;
    const int* ei1 = ei + E_IN;
    float src[4];
#pragma unroll
    for (int h = 0; h < 4; h++) {
        float s = 0.f;
#pragma unroll
        for (int d = 0; d < 8; d++) s += h1[n * 32 + h * 8 + d] * a1s[h * 16 + d];
        src[h] = s;
    }
    float exs[4] = {0.f, 0.f, 0.f, 0.f};
    for (int sl = lane; sl < deg; sl += 64) {
        int e = bucket[n * CAP + sl];
        int col = (e < E_IN) ? ei1[e] : n;
        colL[w][sl] = col;
        float hc[32];
#pragma unroll
        for (int d = 0; d < 32; d++) hc[d] = h1[col * 32 + d];
#pragma unroll
        for (int h = 0; h < 4; h++) {
            float t = src[h];
#pragma unroll
            for (int d = 0; d < 8; d++) t += hc[h * 8 + d] * a1s[h * 16 + 8 + d];
            t = t > 0.f ? t : 0.2f * t;              // leaky relu
            float ex = expf(t);                       // softmax shift-invariant: skip segment-max
            alphaL[w][sl][h] = ex;
            exs[h] += ex;
        }
#pragma unroll
        for (int c = 0; c < 3; c++)
            eaL[w][sl][c] = (e < E_IN) ? ea[(size_t)e * 3 + c] : 1.0f;
    }
#pragma unroll
    for (int h = 0; h < 4; h++) {
        float v = exs[h];
        for (int off = 32; off; off >>= 1) v += __shfl_xor(v, off);
        exs[h] = v + 1e-16f;
    }
    for (int sl = lane; sl < deg; sl += 64) {
        int e = bucket[n * CAP + sl];
        float al[4];
#pragma unroll
        for (int h = 0; h < 4; h++) { al[h] = alphaL[w][sl][h] / exs[h]; alphaL[w][sl][h] = al[h]; }
#pragma unroll
        for (int h = 0; h < 4; h++)
#pragma unroll
            for (int c = 0; c < 3; c++)
                e1[(size_t)e * 12 + h * 3 + c] = al[h] * eaL[w][sl][c];
    }
    __syncthreads();
    for (int o = lane; o < 96; o += 64) {
        int h = o / 24, rem = o % 24, c = rem >> 3, d = rem & 7;
        float acc = 0.f;
        for (int sl = 0; sl < deg; sl++)
            acc += alphaL[w][sl][h] * eaL[w][sl][c] * h1[colL[w][sl] * 32 + h * 8 + d];
        hL1[(size_t)n * 96 + o] = eluf(acc);
    }
}

// ---------- h2 = hL1 @ w2  [3072,96]x[96,8] ----------
__global__ __launch_bounds__(256) void k_gemm2(const float* __restrict__ hL1,
                                               const float* __restrict__ w2,
                                               float* __restrict__ h2) {
    int id = blockIdx.x * 256 + threadIdx.x;   // 96*256 = 24576 = 3072*8
    int n = id >> 3, j = id & 7;
    float acc = 0.f;
#pragma unroll 8
    for (int k = 0; k < 96; k++) acc += hL1[(size_t)n * 96 + k] * w2[k * 8 + j];
    h2[n * 8 + j] = acc;
}

// ---------- EGAT layer 2: one wave per node ----------
__global__ __launch_bounds__(256) void k_egat2(const int* __restrict__ ei,
                                               const float* __restrict__ e1,
                                               const float* __restrict__ a2,
                                               const float* __restrict__ h2,
                                               const int* __restrict__ counts,
                                               const int* __restrict__ bucket,
                                               float* __restrict__ hL2) {
    __shared__ float a2s[16];
    __shared__ float alphaL[4][CAP];
    __shared__ float eL[4][CAP][12];
    __shared__ int   colL[4][CAP];
    int tid = threadIdx.x, w = tid >> 6, lane = tid & 63;
    if (tid < 16) a2s[tid] = a2[tid];
    __syncthreads();
    int n = blockIdx.x * 4 + w;
    int deg = counts[n]; if (deg > CAP) deg = CAP;
    const int* ei1 = ei + E_IN;
    float src = 0.f;
#pragma unroll
    for (int d = 0; d < 8; d++) src += h2[n * 8 + d] * a2s[d];
    float exs = 0.f;
    for (int sl = lane; sl < deg; sl += 64) {
        int e = bucket[n * CAP + sl];
        int col = (e < E_IN) ? ei1[e] : n;
        colL[w][sl] = col;
        float t = src;
#pragma unroll
        for (int d = 0; d < 8; d++) t += h2[col * 8 + d] * a2s[8 + d];
        t = t > 0.f ? t : 0.2f * t;
        float ex = expf(t);
        alphaL[w][sl] = ex; exs += ex;
#pragma unroll
        for (int c = 0; c < 12; c++) eL[w][sl][c] = e1[(size_t)e * 12 + c];
    }
    for (int off = 32; off; off >>= 1) exs += __shfl_xor(exs, off);
    exs += 1e-16f;
    for (int sl = lane; sl < deg; sl += 64) alphaL[w][sl] /= exs;
    __syncthreads();
    for (int o = lane; o < 96; o += 64) {
        int c = o >> 3, d = o & 7;
        float acc = 0.f;
        for (int sl = 0; sl < deg; sl++)
            acc += alphaL[w][sl] * eL[w][sl][c] * h2[colL[w][sl] * 8 + d];
        hL2[(size_t)n * 96 + o] = eluf(acc);
    }
}

// ---------- streaming pass over adj: t accumulation (atomic) + sum(A^2) ----------
// link1 decomposition: sum_c (A_c - P)^2 = sum A^2 - 2*sum_c trace(adj1_c) + 12*||S^T S||_F^2
// grid (3 mtiles of 1024 cols, 12 channels, 32 row-chunks of 96), 256 threads
// thread = 4 consecutive cols (float4); 16 t-accumulators x 4 cols in registers
__global__ __launch_bounds__(256, 4) void k_adj(const float* __restrict__ adj,
                                                const float* __restrict__ s_soft,
                                                float* __restrict__ tmat,
                                                float* __restrict__ scal) {
    __shared__ float snL[96 * 16];
    __shared__ float wsum[4];
    int tid = threadIdx.x;
    int m4 = blockIdx.x * 256 + tid;          // float4 column index (768 per row)
    int c  = blockIdx.y;
    int n0 = blockIdx.z * 96;
    for (int l = tid; l < 1536; l += 256) snL[l] = s_soft[(size_t)n0 * 16 + l];
    const float4* A = (const float4*)(adj + (size_t)c * NNsq);
    float t[16][4];
#pragma unroll
    for (int i = 0; i < 16; i++) { t[i][0] = t[i][1] = t[i][2] = t[i][3] = 0.f; }
    float lsq = 0.f;
    __syncthreads();
    size_t base = (size_t)n0 * 768 + m4;
    for (int nn = 0; nn < 96; nn += 4) {
        float4 a[4];
#pragma unroll
        for (int u = 0; u < 4; u++) a[u] = A[base + (size_t)(nn + u) * 768];
#pragma unroll
        for (int u = 0; u < 4; u++) {
            lsq += a[u].x * a[u].x + a[u].y * a[u].y + a[u].z * a[u].z + a[u].w * a[u].w;
            const float* sn = &snL[(nn + u) * 16];
#pragma unroll
            for (int i = 0; i < 16; i++) {
                float s = sn[i];
                t[i][0] += s * a[u].x; t[i][1] += s * a[u].y;
                t[i][2] += s * a[u].z; t[i][3] += s * a[u].w;
            }
        }
    }
    int m = m4 * 4;
#pragma unroll
    for (int i = 0; i < 16; i++) {
        float* dst = &tmat[((size_t)c * 16 + i) * 3072 + m];
        atomicAdd(dst + 0, t[i][0]); atomicAdd(dst + 1, t[i][1]);
        atomicAdd(dst + 2, t[i][2]); atomicAdd(dst + 3, t[i][3]);
    }
    for (int off = 32; off; off >>= 1) lsq += __shfl_xor(lsq, off);
    if ((tid & 63) == 0) wsum[tid >> 6] = lsq;
    __syncthreads();
    if (tid == 0) atomicAdd(&scal[0], wsum[0] + wsum[1] + wsum[2] + wsum[3]);
}

// ---------- adj1[c,i,j] = sum_m t[c,i,m] s[m,j]; (adj1-1)^2 -> link2; trace -> cross ----------
__global__ __launch_bounds__(256) void k_adj2(const float* __restrict__ tmat,
                                              const float* __restrict__ s_soft,
                                              float* __restrict__ scal) {
    int b = blockIdx.x;   // 192 = 12*16  -> (c,i)
    int tid = threadIdx.x;
    const float* trow = tmat + (size_t)b * 3072;
    float acc[16];
#pragma unroll
    for (int j = 0; j < 16; j++) acc[j] = 0.f;
    for (int m = tid; m < 3072; m += 256) {
        float tv = trow[m];
#pragma unroll
        for (int j = 0; j < 16; j++) acc[j] += tv * s_soft[m * 16 + j];
    }
    __shared__ float wpart[16][4];
#pragma unroll
    for (int j = 0; j < 16; j++) {
        float v = acc[j];
        for (int off = 32; off; off >>= 1) v += __shfl_xor(v, off);
        if ((tid & 63) == 0) wpart[j][tid >> 6] = v;
    }
    __syncthreads();
    if (tid < 16) {
        float v = wpart[tid][0] + wpart[tid][1] + wpart[tid][2] + wpart[tid][3];
        float d = v - 1.0f;
        atomicAdd(&scal[1], d * d);
        if (tid == (b & 15)) atomicAdd(&scal[3], v);   // trace(adj1_c) for cross term
    }
}

// ---------- pooled x collapses to column sum of hL2 (softmax rows sum to 1; s2 softmax == 1)
__global__ __launch_bounds__(256) void k_colsum(const float* __restrict__ hL2,
                                                float* __restrict__ xfin) {
    int f = blockIdx.x;   // 96
    int tid = threadIdx.x;
    float s = 0.f;
    for (int n = tid; n < 3072; n += 256) s += hL2[(size_t)n * 96 + f];
    __shared__ float wsum[4];
    for (int off = 32; off; off >>= 1) s += __shfl_xor(s, off);
    if ((tid & 63) == 0) wsum[tid >> 6] = s;
    __syncthreads();
    if (tid == 0) xfin[f] = wsum[0] + wsum[1] + wsum[2] + wsum[3];
}

// ---------- FC head + log_softmax + regs ----------
__global__ void k_fc(const float* __restrict__ xfin,
                     const float* __restrict__ w1, const float* __restrict__ b1,
                     const float* __restrict__ w2, const float* __restrict__ b2,
                     const float* __restrict__ w3, const float* __restrict__ b3,
                     const float* __restrict__ w4, const float* __restrict__ b4,
                     const float* __restrict__ scal, const float* __restrict__ Mbuf,
                     float* __restrict__ out) {
    __shared__ float xf[96], z1[128], z2[32], z3[16], z4[2];
    __shared__ float msqs[2];
    int t = threadIdx.x;  // 128 threads
    {   // ||M||_F^2 = sum_nm P^2 (parallel reduce over 256 entries)
        float m1 = Mbuf[t], m2 = Mbuf[t + 128];
        float msq = m1 * m1 + m2 * m2;
        for (int off = 32; off; off >>= 1) msq += __shfl_xor(msq, off);
        if ((t & 63) == 0) msqs[t >> 6] = msq;
    }
    if (t < 96) xf[t] = xfin[t];
    __syncthreads();
    {
        float a = b1[t];
        for (int k = 0; k < 96; k++) a += xf[k] * w1[k * 128 + t];
        z1[t] = eluf(a);
    }
    __syncthreads();
    if (t < 32) {
        float a = b2[t];
        for (int k = 0; k < 128; k++) a += z1[k] * w2[k * 32 + t];
        z2[t] = eluf(a);
    }
    __syncthreads();
    if (t < 16) {
        float a = b3[t];
        for (int k = 0; k < 32; k++) a += z2[k] * w3[k * 16 + t];
        z3[t] = eluf(a);
    }
    __syncthreads();
    if (t < 2) {
        float a = b4[t];
        for (int k = 0; k < 16; k++) a += z3[k] * w4[k * 2 + t];
        z4[t] = a;
    }
    __syncthreads();
    if (t == 0) {
        float mx = fmaxf(z4[0], z4[1]);
        float lse = mx + logf(expf(z4[0] - mx) + expf(z4[1] - mx));
        out[0] = z4[0] - lse;
        out[1] = z4[1] - lse;
        float ent1 = -scal[2] / 3072.0f;
        float sumP2 = msqs[0] + msqs[1];
        float linksq = scal[0] - 2.0f * scal[3] + 12.0f * sumP2;
        float link1 = sqrtf(fmaxf(linksq, 0.f)) / 113246208.0f;   // adj.size = 12*3072*3072
        out[2] = link1 + ent1;
        float link2 = sqrtf(scal[1]) / 3072.0f;        // ent2 = -log(1+1e-15) ~ 0
        out[3] = link2;
    }
}

extern "C" void kernel_launch(void* const* d_in, const int* in_sizes, int n_in,
                              void* d_out, int out_size, void* d_ws, size_t ws_size,
                              hipStream_t stream) {
    const float* x    = (const float*)d_in[0];
    const int*   ei   = (const int*)d_in[1];
    const float* ea   = (const float*)d_in[2];
    const float* adj  = (const float*)d_in[3];
    const float* w1   = (const float*)d_in[4];
    const float* a1   = (const float*)d_in[5];
    const float* w2   = (const float*)d_in[6];
    const float* a2   = (const float*)d_in[7];
    const float* s1   = (const float*)d_in[8];
    // d_in[9] = s2: softmax over axis of size 1 == 1.0, unused
    const float* fc1w = (const float*)d_in[10];
    const float* fc1b = (const float*)d_in[11];
    const float* fc2w = (const float*)d_in[12];
    const float* fc2b = (const float*)d_in[13];
    const float* fc3w = (const float*)d_in[14];
    const float* fc3b = (const float*)d_in[15];
    const float* fc4w = (const float*)d_in[16];
    const float* fc4b = (const float*)d_in[17];
    float* out = (float*)d_out;

    // compact workspace layout (~12 MB total)
    float* ws     = (float*)d_ws;
    float* tmat   = ws;                              // 12*16*3072 = 589824
    float* xfin   = tmat + 589824;                   // 96
    float* scal   = xfin + 96;                       // [sumA2, link2sq, entsum, cross] + pad
    float* Mbuf   = scal + 8;                        // 256 (M = S^T S partials)
    int*   counts = (int*)(Mbuf + 256);              // 3072
    int*   bucket = counts + 3072;                   // 3072*CAP
    float* s_soft = (float*)(bucket + 3072 * CAP);   // 3072*16
    float* h1     = s_soft + 3072 * 16;              // 3072*32
    float* hL1    = h1 + 3072 * 32;                  // 3072*96
    float* h2     = hL1 + 3072 * 96;                 // 3072*8
    float* hL2    = h2 + 3072 * 8;                   // 3072*96
    float* e1     = hL2 + 3072 * 96;                 // EP*12

    // zero tmat + xfin + scal + Mbuf + counts in one contiguous memset
    hipMemsetAsync(tmat, 0, (589824 + 96 + 8 + 256) * sizeof(float) + 3072 * sizeof(int), stream);

    k_softmax<<<12, 256, 0, stream>>>(s1, s_soft, scal);
    k_psq<<<12, 256, 0, stream>>>(s_soft, Mbuf);
    k_bucket<<<(EP + 255) / 256, 256, 0, stream>>>(ei, counts, bucket);
    k_gemm1<<<384, 256, 0, stream>>>(x, w1, h1);
    k_egat1<<<768, 256, 0, stream>>>(ei, ea, a1, h1, counts, bucket, e1, hL1);
    k_gemm2<<<96, 256, 0, stream>>>(hL1, w2, h2);
    k_egat2<<<768, 256, 0, stream>>>(ei, e1, a2, h2, counts, bucket, hL2);
    k_adj<<<dim3(3, 12, 32), 256, 0, stream>>>(adj, s_soft, tmat, scal);
    k_adj2<<<192, 256, 0, stream>>>(tmat, s_soft, scal);
    k_colsum<<<96, 256, 0, stream>>>(hL2, xfin);
    k_fc<<<1, 128, 0, stream>>>(xfin, fc1w, fc1b, fc2w, fc2b, fc3w, fc3b, fc4w, fc4b, scal, Mbuf, out);
}

// Round 2
// 789.079 us; speedup vs baseline: 1.1977x; 1.1977x over previous
//
#include <hip/hip_runtime.h>
#include <hip/hip_bf16.h>

#define Nn 3072
#define E_IN 98304
#define EP (E_IN + Nn)      // 101376 edges incl self loops
#define CAP 128             // per-node bucket capacity (Poisson(32) -> never exceeded)
#define NNsq ((size_t)Nn * (size_t)Nn)

__device__ __forceinline__ float eluf(float a) { return a > 0.f ? a : (expf(a) - 1.f); }

// ---------- softmax of s1 rows + entropy partial ----------
__global__ __launch_bounds__(256) void k_softmax(const float* __restrict__ s1,
                                                 float* __restrict__ s_soft,
                                                 float* __restrict__ scal) {
    int n = blockIdx.x * 256 + threadIdx.x;   // 12*256 = 3072
    float v[16], mx = -1e30f;
#pragma unroll
    for (int i = 0; i < 16; i++) { v[i] = s1[n * 16 + i]; mx = fmaxf(mx, v[i]); }
    float s = 0.f;
#pragma unroll
    for (int i = 0; i < 16; i++) { v[i] = expf(v[i] - mx); s += v[i]; }
    float inv = 1.f / s, ent = 0.f;
#pragma unroll
    for (int i = 0; i < 16; i++) {
        float p = v[i] * inv;
        s_soft[n * 16 + i] = p;
        ent += p * logf(p + 1e-15f);
    }
    __shared__ float wsum[4];
    for (int off = 32; off; off >>= 1) ent += __shfl_xor(ent, off);
    if ((threadIdx.x & 63) == 0) wsum[threadIdx.x >> 6] = ent;
    __syncthreads();
    if (threadIdx.x == 0) atomicAdd(&scal[2], wsum[0] + wsum[1] + wsum[2] + wsum[3]);
}

// ---------- M = S^T S partials -> Mbuf[256]; sum(M^2) = sum_nm P^2 done in k_fc ----------
__global__ __launch_bounds__(256) void k_psq(const float* __restrict__ s_soft,
                                             float* __restrict__ Mbuf) {
    __shared__ float sL[256 * 16];            // 16 KB: 256 rows of s
    int tid = threadIdx.x;
    int n0 = blockIdx.x * 256;                // 12 blocks
    for (int l = tid; l < 4096; l += 256) sL[l] = s_soft[(size_t)n0 * 16 + l];
    __syncthreads();
    int i = tid >> 4, j = tid & 15;
    float acc = 0.f;
#pragma unroll 8
    for (int n = 0; n < 256; n++) acc += sL[n * 16 + i] * sL[n * 16 + j];
    atomicAdd(&Mbuf[tid], acc);
}

// ---------- bucket edges by destination (row) ----------
__global__ void k_bucket(const int* __restrict__ ei, int* __restrict__ counts,
                         int* __restrict__ bucket) {
    int e = blockIdx.x * 256 + threadIdx.x;   // 396*256 = 101376
    if (e >= EP) return;
    int r = (e < E_IN) ? ei[e] : (e - E_IN);
    int pos = atomicAdd(&counts[r], 1);
    if (pos < CAP) bucket[r * CAP + pos] = e;
}

// ---------- h1 = x @ w1  [3072,128]x[128,32] ----------
__global__ __launch_bounds__(256) void k_gemm1(const float* __restrict__ x,
                                               const float* __restrict__ w1,
                                               float* __restrict__ h1) {
    __shared__ float xs[8 * 128];
    int n0 = blockIdx.x * 8;
    for (int idx = threadIdx.x; idx < 1024; idx += 256) xs[idx] = x[(size_t)n0 * 128 + idx];
    __syncthreads();
    int r = threadIdx.x >> 5, j = threadIdx.x & 31;
    float acc = 0.f;
#pragma unroll 8
    for (int k = 0; k < 128; k++) acc += xs[r * 128 + k] * w1[k * 32 + j];
    h1[(n0 + r) * 32 + j] = acc;
}

// ---------- EGAT layer 1: one wave per node ----------
__global__ __launch_bounds__(256) void k_egat1(const int* __restrict__ ei,
                                               const float* __restrict__ ea,
                                               const float* __restrict__ a1,
                                               const float* __restrict__ h1,
                                               const int* __restrict__ counts,
                                               const int* __restrict__ bucket,
                                               float* __restrict__ e1,
                                               float* __restrict__ hL1) {
    __shared__ float a1s[64];
    __shared__ float alphaL[4][CAP][4];
    __shared__ float eaL[4][CAP][3];
    __shared__ int   colL[4][CAP];
    int tid = threadIdx.x, w = tid >> 6, lane = tid & 63;
    if (tid < 64) a1s[tid] = a1[tid];
    __syncthreads();
    int n = blockIdx.x * 4 + w;
    int deg = counts[n]; if (deg > CAP) deg = CAP;
    const int* ei1 = ei + E_IN;
    float src[4];
#pragma unroll
    for (int h = 0; h < 4; h++) {
        float s = 0.f;
#pragma unroll
        for (int d = 0; d < 8; d++) s += h1[n * 32 + h * 8 + d] * a1s[h * 16 + d];
        src[h] = s;
    }
    float exs[4] = {0.f, 0.f, 0.f, 0.f};
    for (int sl = lane; sl < deg; sl += 64) {
        int e = bucket[n * CAP + sl];
        int col = (e < E_IN) ? ei1[e] : n;
        colL[w][sl] = col;
        float hc[32];
#pragma unroll
        for (int d = 0; d < 32; d++) hc[d] = h1[col * 32 + d];
#pragma unroll
        for (int h = 0; h < 4; h++) {
            float t = src[h];
#pragma unroll
            for (int d = 0; d < 8; d++) t += hc[h * 8 + d] * a1s[h * 16 + 8 + d];
            t = t > 0.f ? t : 0.2f * t;              // leaky relu
            float ex = expf(t);                       // softmax shift-invariant: skip segment-max
            alphaL[w][sl][h] = ex;
            exs[h] += ex;
        }
#pragma unroll
        for (int c = 0; c < 3; c++)
            eaL[w][sl][c] = (e < E_IN) ? ea[(size_t)e * 3 + c] : 1.0f;
    }
#pragma unroll
    for (int h = 0; h < 4; h++) {
        float v = exs[h];
        for (int off = 32; off; off >>= 1) v += __shfl_xor(v, off);
        exs[h] = v + 1e-16f;
    }
    for (int sl = lane; sl < deg; sl += 64) {
        int e = bucket[n * CAP + sl];
        float al[4];
#pragma unroll
        for (int h = 0; h < 4; h++) { al[h] = alphaL[w][sl][h] / exs[h]; alphaL[w][sl][h] = al[h]; }
#pragma unroll
        for (int h = 0; h < 4; h++)
#pragma unroll
            for (int c = 0; c < 3; c++)
                e1[(size_t)e * 12 + h * 3 + c] = al[h] * eaL[w][sl][c];
    }
    __syncthreads();
    for (int o = lane; o < 96; o += 64) {
        int h = o / 24, rem = o % 24, c = rem >> 3, d = rem & 7;
        float acc = 0.f;
        for (int sl = 0; sl < deg; sl++)
            acc += alphaL[w][sl][h] * eaL[w][sl][c] * h1[colL[w][sl] * 32 + h * 8 + d];
        hL1[(size_t)n * 96 + o] = eluf(acc);
    }
}

// ---------- h2 = hL1 @ w2  [3072,96]x[96,8] ----------
__global__ __launch_bounds__(256) void k_gemm2(const float* __restrict__ hL1,
                                               const float* __restrict__ w2,
                                               float* __restrict__ h2) {
    int id = blockIdx.x * 256 + threadIdx.x;   // 96*256 = 24576 = 3072*8
    int n = id >> 3, j = id & 7;
    float acc = 0.f;
#pragma unroll 8
    for (int k = 0; k < 96; k++) acc += hL1[(size_t)n * 96 + k] * w2[k * 8 + j];
    h2[n * 8 + j] = acc;
}

// ---------- EGAT layer 2: one wave per node ----------
__global__ __launch_bounds__(256) void k_egat2(const int* __restrict__ ei,
                                               const float* __restrict__ e1,
                                               const float* __restrict__ a2,
                                               const float* __restrict__ h2,
                                               const int* __restrict__ counts,
                                               const int* __restrict__ bucket,
                                               float* __restrict__ hL2) {
    __shared__ float a2s[16];
    __shared__ float alphaL[4][CAP];
    __shared__ float eL[4][CAP][12];
    __shared__ int   colL[4][CAP];
    int tid = threadIdx.x, w = tid >> 6, lane = tid & 63;
    if (tid < 16) a2s[tid] = a2[tid];
    __syncthreads();
    int n = blockIdx.x * 4 + w;
    int deg = counts[n]; if (deg > CAP) deg = CAP;
    const int* ei1 = ei + E_IN;
    float src = 0.f;
#pragma unroll
    for (int d = 0; d < 8; d++) src += h2[n * 8 + d] * a2s[d];
    float exs = 0.f;
    for (int sl = lane; sl < deg; sl += 64) {
        int e = bucket[n * CAP + sl];
        int col = (e < E_IN) ? ei1[e] : n;
        colL[w][sl] = col;
        float t = src;
#pragma unroll
        for (int d = 0; d < 8; d++) t += h2[col * 8 + d] * a2s[8 + d];
        t = t > 0.f ? t : 0.2f * t;
        float ex = expf(t);
        alphaL[w][sl] = ex; exs += ex;
#pragma unroll
        for (int c = 0; c < 12; c++) eL[w][sl][c] = e1[(size_t)e * 12 + c];
    }
    for (int off = 32; off; off >>= 1) exs += __shfl_xor(exs, off);
    exs += 1e-16f;
    for (int sl = lane; sl < deg; sl += 64) alphaL[w][sl] /= exs;
    __syncthreads();
    for (int o = lane; o < 96; o += 64) {
        int c = o >> 3, d = o & 7;
        float acc = 0.f;
        for (int sl = 0; sl < deg; sl++)
            acc += alphaL[w][sl] * eL[w][sl][c] * h2[colL[w][sl] * 8 + d];
        hL2[(size_t)n * 96 + o] = eluf(acc);
    }
}

// ---------- streaming pass over adj: t accumulation + sum(A^2) ----------
// link1 decomposition: sum_c (A_c - P)^2 = sum A^2 - 2*sum_c trace(adj1_c) + 12*||S^T S||_F^2
// grid (3 mtiles of 1024 cols, 12 channels, 16 row-chunks of 192), 256 threads
// thread = 4 consecutive cols (float4); 8 float4 loads in flight per iteration.
// Atomic epilogue goes through an LDS transpose so each wave-atomic is lane-contiguous
// (4B stride) -> no sector write amplification (v2 lesson: 16B-stride atomics = 4x writes).
__global__ __launch_bounds__(256, 4) void k_adj(const float* __restrict__ adj,
                                                const float* __restrict__ s_soft,
                                                float* __restrict__ tmat,
                                                float* __restrict__ scal) {
    __shared__ float snL[192 * 16];
    __shared__ float xbuf[1024];
    __shared__ float wsum[4];
    int tid = threadIdx.x;
    int m4 = blockIdx.x * 256 + tid;          // float4 column index (768 per row)
    int c  = blockIdx.y;
    int n0 = blockIdx.z * 192;
    for (int l = tid; l < 3072; l += 256) snL[l] = s_soft[(size_t)n0 * 16 + l];
    const float4* A = (const float4*)(adj + (size_t)c * NNsq);
    float t[16][4];
#pragma unroll
    for (int i = 0; i < 16; i++) { t[i][0] = t[i][1] = t[i][2] = t[i][3] = 0.f; }
    float lsq = 0.f;
    __syncthreads();
    const float4* Arow = A + (size_t)n0 * 768 + m4;
    for (int nn = 0; nn < 192; nn += 8) {
        float4 a[8];
#pragma unroll
        for (int u = 0; u < 8; u++) a[u] = Arow[(size_t)(nn + u) * 768];
#pragma unroll
        for (int u = 0; u < 8; u++) {
            lsq += a[u].x * a[u].x + a[u].y * a[u].y + a[u].z * a[u].z + a[u].w * a[u].w;
            const float* sn = &snL[(nn + u) * 16];
#pragma unroll
            for (int i = 0; i < 16; i++) {
                float s = sn[i];
                t[i][0] += s * a[u].x; t[i][1] += s * a[u].y;
                t[i][2] += s * a[u].z; t[i][3] += s * a[u].w;
            }
        }
    }
    // epilogue: LDS-transpose so atomic lanes are 4B-contiguous
    int m0 = blockIdx.x * 1024;
#pragma unroll 1
    for (int i = 0; i < 16; i++) {
        __syncthreads();
        xbuf[tid * 4 + 0] = t[i][0]; xbuf[tid * 4 + 1] = t[i][1];
        xbuf[tid * 4 + 2] = t[i][2]; xbuf[tid * 4 + 3] = t[i][3];
        __syncthreads();
        float* dst = &tmat[((size_t)c * 16 + i) * 3072 + m0];
        atomicAdd(&dst[tid      ], xbuf[tid      ]);
        atomicAdd(&dst[tid + 256], xbuf[tid + 256]);
        atomicAdd(&dst[tid + 512], xbuf[tid + 512]);
        atomicAdd(&dst[tid + 768], xbuf[tid + 768]);
    }
    for (int off = 32; off; off >>= 1) lsq += __shfl_xor(lsq, off);
    if ((tid & 63) == 0) wsum[tid >> 6] = lsq;
    __syncthreads();
    if (tid == 0) atomicAdd(&scal[0], wsum[0] + wsum[1] + wsum[2] + wsum[3]);
}

// ---------- adj1[c,i,j] = sum_m t[c,i,m] s[m,j]; (adj1-1)^2 -> link2; trace -> cross ----------
__global__ __launch_bounds__(256) void k_adj2(const float* __restrict__ tmat,
                                              const float* __restrict__ s_soft,
                                              float* __restrict__ scal) {
    int b = blockIdx.x;   // 192 = 12*16  -> (c,i)
    int tid = threadIdx.x;
    const float* trow = tmat + (size_t)b * 3072;
    float acc[16];
#pragma unroll
    for (int j = 0; j < 16; j++) acc[j] = 0.f;
    for (int m = tid; m < 3072; m += 256) {
        float tv = trow[m];
#pragma unroll
        for (int j = 0; j < 16; j++) acc[j] += tv * s_soft[m * 16 + j];
    }
    __shared__ float wpart[16][4];
#pragma unroll
    for (int j = 0; j < 16; j++) {
        float v = acc[j];
        for (int off = 32; off; off >>= 1) v += __shfl_xor(v, off);
        if ((tid & 63) == 0) wpart[j][tid >> 6] = v;
    }
    __syncthreads();
    if (tid < 16) {
        float v = wpart[tid][0] + wpart[tid][1] + wpart[tid][2] + wpart[tid][3];
        float d = v - 1.0f;
        atomicAdd(&scal[1], d * d);
        if (tid == (b & 15)) atomicAdd(&scal[3], v);   // trace(adj1_c) for cross term
    }
}

// ---------- pooled x collapses to column sum of hL2 (softmax rows sum to 1; s2 softmax == 1)
__global__ __launch_bounds__(256) void k_colsum(const float* __restrict__ hL2,
                                                float* __restrict__ xfin) {
    int f = blockIdx.x;   // 96
    int tid = threadIdx.x;
    float s = 0.f;
    for (int n = tid; n < 3072; n += 256) s += hL2[(size_t)n * 96 + f];
    __shared__ float wsum[4];
    for (int off = 32; off; off >>= 1) s += __shfl_xor(s, off);
    if ((tid & 63) == 0) wsum[tid >> 6] = s;
    __syncthreads();
    if (tid == 0) xfin[f] = wsum[0] + wsum[1] + wsum[2] + wsum[3];
}

// ---------- FC head + log_softmax + regs ----------
__global__ void k_fc(const float* __restrict__ xfin,
                     const float* __restrict__ w1, const float* __restrict__ b1,
                     const float* __restrict__ w2, const float* __restrict__ b2,
                     const float* __restrict__ w3, const float* __restrict__ b3,
                     const float* __restrict__ w4, const float* __restrict__ b4,
                     const float* __restrict__ scal, const float* __restrict__ Mbuf,
                     float* __restrict__ out) {
    __shared__ float xf[96], z1[128], z2[32], z3[16], z4[2];
    __shared__ float msqs[2];
    int t = threadIdx.x;  // 128 threads
    {   // ||M||_F^2 = sum_nm P^2 (parallel reduce over 256 entries)
        float m1 = Mbuf[t], m2 = Mbuf[t + 128];
        float msq = m1 * m1 + m2 * m2;
        for (int off = 32; off; off >>= 1) msq += __shfl_xor(msq, off);
        if ((t & 63) == 0) msqs[t >> 6] = msq;
    }
    if (t < 96) xf[t] = xfin[t];
    __syncthreads();
    {
        float a = b1[t];
        for (int k = 0; k < 96; k++) a += xf[k] * w1[k * 128 + t];
        z1[t] = eluf(a);
    }
    __syncthreads();
    if (t < 32) {
        float a = b2[t];
        for (int k = 0; k < 128; k++) a += z1[k] * w2[k * 32 + t];
        z2[t] = eluf(a);
    }
    __syncthreads();
    if (t < 16) {
        float a = b3[t];
        for (int k = 0; k < 32; k++) a += z2[k] * w3[k * 16 + t];
        z3[t] = eluf(a);
    }
    __syncthreads();
    if (t < 2) {
        float a = b4[t];
        for (int k = 0; k < 16; k++) a += z3[k] * w4[k * 2 + t];
        z4[t] = a;
    }
    __syncthreads();
    if (t == 0) {
        float mx = fmaxf(z4[0], z4[1]);
        float lse = mx + logf(expf(z4[0] - mx) + expf(z4[1] - mx));
        out[0] = z4[0] - lse;
        out[1] = z4[1] - lse;
        float ent1 = -scal[2] / 3072.0f;
        float sumP2 = msqs[0] + msqs[1];
        float linksq = scal[0] - 2.0f * scal[3] + 12.0f * sumP2;
        float link1 = sqrtf(fmaxf(linksq, 0.f)) / 113246208.0f;   // adj.size = 12*3072*3072
        out[2] = link1 + ent1;
        float link2 = sqrtf(scal[1]) / 3072.0f;        // ent2 = -log(1+1e-15) ~ 0
        out[3] = link2;
    }
}

extern "C" void kernel_launch(void* const* d_in, const int* in_sizes, int n_in,
                              void* d_out, int out_size, void* d_ws, size_t ws_size,
                              hipStream_t stream) {
    const float* x    = (const float*)d_in[0];
    const int*   ei   = (const int*)d_in[1];
    const float* ea   = (const float*)d_in[2];
    const float* adj  = (const float*)d_in[3];
    const float* w1   = (const float*)d_in[4];
    const float* a1   = (const float*)d_in[5];
    const float* w2   = (const float*)d_in[6];
    const float* a2   = (const float*)d_in[7];
    const float* s1   = (const float*)d_in[8];
    // d_in[9] = s2: softmax over axis of size 1 == 1.0, unused
    const float* fc1w = (const float*)d_in[10];
    const float* fc1b = (const float*)d_in[11];
    const float* fc2w = (const float*)d_in[12];
    const float* fc2b = (const float*)d_in[13];
    const float* fc3w = (const float*)d_in[14];
    const float* fc3b = (const float*)d_in[15];
    const float* fc4w = (const float*)d_in[16];
    const float* fc4b = (const float*)d_in[17];
    float* out = (float*)d_out;

    // compact workspace layout (~12 MB total)
    float* ws     = (float*)d_ws;
    float* tmat   = ws;                              // 12*16*3072 = 589824
    float* xfin   = tmat + 589824;                   // 96
    float* scal   = xfin + 96;                       // [sumA2, link2sq, entsum, cross] + pad
    float* Mbuf   = scal + 8;                        // 256 (M = S^T S partials)
    int*   counts = (int*)(Mbuf + 256);              // 3072
    int*   bucket = counts + 3072;                   // 3072*CAP
    float* s_soft = (float*)(bucket + 3072 * CAP);   // 3072*16
    float* h1     = s_soft + 3072 * 16;              // 3072*32
    float* hL1    = h1 + 3072 * 32;                  // 3072*96
    float* h2     = hL1 + 3072 * 96;                 // 3072*8
    float* hL2    = h2 + 3072 * 8;                   // 3072*96
    float* e1     = hL2 + 3072 * 96;                 // EP*12

    // zero tmat + xfin + scal + Mbuf + counts in one contiguous memset
    hipMemsetAsync(tmat, 0, (589824 + 96 + 8 + 256) * sizeof(float) + 3072 * sizeof(int), stream);

    k_softmax<<<12, 256, 0, stream>>>(s1, s_soft, scal);
    k_psq<<<12, 256, 0, stream>>>(s_soft, Mbuf);
    k_bucket<<<(EP + 255) / 256, 256, 0, stream>>>(ei, counts, bucket);
    k_gemm1<<<384, 256, 0, stream>>>(x, w1, h1);
    k_egat1<<<768, 256, 0, stream>>>(ei, ea, a1, h1, counts, bucket, e1, hL1);
    k_gemm2<<<96, 256, 0, stream>>>(hL1, w2, h2);
    k_egat2<<<768, 256, 0, stream>>>(ei, e1, a2, h2, counts, bucket, hL2);
    k_adj<<<dim3(3, 12, 16), 256, 0, stream>>>(adj, s_soft, tmat, scal);
    k_adj2<<<192, 256, 0, stream>>>(tmat, s_soft, scal);
    k_colsum<<<96, 256, 0, stream>>>(hL2, xfin);
    k_fc<<<1, 128, 0, stream>>>(xfin, fc1w, fc1b, fc2w, fc2b, fc3w, fc3b, fc4w, fc4b, scal, Mbuf, out);
}